// Round 2
// baseline (182.803 us; speedup 1.0000x reference)
//
#include <hip/hip_runtime.h>
#include <math.h>

// Problem constants (B,S,D,V,C) = (32, 2048, 512, 32000, 2)
#define BB 32
#define SS 2048
#define DD 512
#define VV 32000
#define JT 36          // 32 q-rows + w0 + w1 + 2 zero pad (and LDS pad stride: 36 floats = 9 float4)
#define RB 256         // vocab rows per score block
#define DH 256         // dims per half (grid.y split)
#define NT 8           // d-tiles per half (32 dims each)

// ---------------------------------------------------------------------------
// Pass 0: build QT[36][512] = { q_0..q_31 (= emb[tokens[b,0]]), w0, w1, 0, 0 }
// ---------------------------------------------------------------------------
__global__ __launch_bounds__(128) void build_qt(
    const int* __restrict__ tokens, const float* __restrict__ emb,
    const float* __restrict__ cls_w, float* __restrict__ QT)
{
    const int j   = blockIdx.x;    // 0..35
    const int tid = threadIdx.x;   // 128 threads * float4 = 512 floats
    float4 v = make_float4(0.f, 0.f, 0.f, 0.f);
    if (j < 32) {
        const int tok = tokens[(size_t)j * SS];
        v = ((const float4*)(emb + (size_t)tok * DD))[tid];
    } else if (j < 34) {
        v = ((const float4*)(cls_w + (size_t)(j - 32) * DD))[tid];
    }
    ((float4*)QT)[j * (DD / 4) + tid] = v;
}

// ---------------------------------------------------------------------------
// Pass A: stream the embedding table ONCE, computing all 36 dots per vocab row.
// Sh[h][v][j] = sum_{d in half h} emb[v][d] * QT[j][d]
// Block: 256 rows x one 256-dim half. Thread: 4 rows x 9 j's register tile.
//   rowg = tid>>2 (rows rowg + {0,64,128,192}),  jg = tid&3 (j's jg*9..jg*9+8)
// LDS row tile [256][36] (stride 36 floats = 144 B, 16B-aligned; compute reads
// are 2-way bank aliased = free; q reads are 4-address broadcast = free).
// ---------------------------------------------------------------------------
__global__ __launch_bounds__(256) void score_pass(
    const float* __restrict__ emb, const float* __restrict__ QT,
    float* __restrict__ Sh)
{
    const int bx   = blockIdx.x;       // 0..124 (125*256 = 32000 exactly)
    const int h    = blockIdx.y;       // 0..1 dim half
    const int tid  = threadIdx.x;
    const int rowg = tid >> 2;         // 0..63
    const int jg   = tid & 3;          // 0..3

    __shared__ float rt[RB][36];       // row tile: 256 rows x 32 dims (+pad)
    __shared__ float qt[JT][36];       // q tile:   36 j    x 32 dims (+pad)

    const int v0     = bx * RB;
    const int dbase4 = (h * DH) >> 2;  // float4 offset of this dim half

    float acc[4][9];
#pragma unroll
    for (int k = 0; k < 4; ++k)
#pragma unroll
        for (int jj = 0; jj < 9; ++jj) acc[k][jj] = 0.f;

    const float4* emb4 = (const float4*)emb;
    const float4* QT4  = (const float4*)QT;

    // register-staged prefetch (T14): rows 8 x float4/thread, q 0-2 x float4
    float4 pr[8];
    float4 pq[2];

    // load tile 0
    {
        const int t4 = dbase4;
#pragma unroll
        for (int u = 0; u < 8; ++u) {
            const int f = u * 256 + tid, r = f >> 3, dq = f & 7;
            pr[u] = emb4[(size_t)(v0 + r) * (DD / 4) + t4 + dq];
        }
#pragma unroll
        for (int u = 0; u < 2; ++u) {
            const int f = u * 256 + tid;
            if (f < JT * 8) {
                const int j = f >> 3, dq = f & 7;
                pq[u] = QT4[j * (DD / 4) + t4 + dq];
            }
        }
    }

    for (int tt = 0; tt < NT; ++tt) {
        // write staged registers to LDS
#pragma unroll
        for (int u = 0; u < 8; ++u) {
            const int f = u * 256 + tid, r = f >> 3, dq = f & 7;
            *(float4*)&rt[r][dq * 4] = pr[u];
        }
#pragma unroll
        for (int u = 0; u < 2; ++u) {
            const int f = u * 256 + tid;
            if (f < JT * 8) {
                const int j = f >> 3, dq = f & 7;
                *(float4*)&qt[j][dq * 4] = pq[u];
            }
        }
        __syncthreads();

        // issue next tile's global loads (latency hides under the FMAs below)
        if (tt + 1 < NT) {
            const int t4 = dbase4 + (tt + 1) * 8;
#pragma unroll
            for (int u = 0; u < 8; ++u) {
                const int f = u * 256 + tid, r = f >> 3, dq = f & 7;
                pr[u] = emb4[(size_t)(v0 + r) * (DD / 4) + t4 + dq];
            }
#pragma unroll
            for (int u = 0; u < 2; ++u) {
                const int f = u * 256 + tid;
                if (f < JT * 8) {
                    const int j = f >> 3, dq = f & 7;
                    pq[u] = QT4[j * (DD / 4) + t4 + dq];
                }
            }
        }

        // compute: 8 chunks of 4 dims; per chunk 13 ds_read_b128 + 144 FMA
#pragma unroll
        for (int c = 0; c < 8; ++c) {
            float4 x[4];
#pragma unroll
            for (int k = 0; k < 4; ++k)
                x[k] = *(const float4*)&rt[rowg + 64 * k][c * 4];
            float4 qv[9];
#pragma unroll
            for (int jj = 0; jj < 9; ++jj)
                qv[jj] = *(const float4*)&qt[jg * 9 + jj][c * 4];
#pragma unroll
            for (int k = 0; k < 4; ++k)
#pragma unroll
                for (int jj = 0; jj < 9; ++jj)
                    acc[k][jj] += x[k].x * qv[jj].x + x[k].y * qv[jj].y
                                + x[k].z * qv[jj].z + x[k].w * qv[jj].w;
        }
        __syncthreads();
    }

    // write partial dots (each (h, row, j) owned by exactly one thread)
    float* outp = Sh + (size_t)h * VV * JT;
#pragma unroll
    for (int k = 0; k < 4; ++k) {
        float* dst = outp + (size_t)(v0 + rowg + 64 * k) * JT + jg * 9;
#pragma unroll
        for (int jj = 0; jj < 9; ++jj) dst[jj] = acc[k][jj];
    }
}

// ---------------------------------------------------------------------------
// Pass B: per batch, gather {s,u,v} per token (6 floats from the 9 MB score
// table, L2-hot), exp-sum, and emit the two logits directly.
// ---------------------------------------------------------------------------
__global__ __launch_bounds__(256) void gather_pass(
    const int* __restrict__ tokens, const float* __restrict__ Sh,
    const float* __restrict__ cls_b, float* __restrict__ out)
{
    const int b   = blockIdx.x;
    const int tid = threadIdx.x;
    const float* S0 = Sh;
    const float* S1 = Sh + (size_t)VV * JT;

    float L = 0.f, d0 = 0.f, d1 = 0.f;
#pragma unroll
    for (int i = 0; i < 8; ++i) {
        const int t   = tid * 8 + i;               // 256 threads x 8 = 2048
        const int tok = tokens[(size_t)b * SS + t];
        const float* r0 = S0 + (size_t)tok * JT;
        const float* r1 = S1 + (size_t)tok * JT;
        const float s = r0[b]  + r1[b];            // q_b . x_t
        const float u = r0[32] + r1[32];           // w0 . x_t
        const float v = r0[33] + r1[33];           // w1 . x_t
        const float p = __expf(s);                  // bounded |s| <~ 0.3
        L += p; d0 += p * u; d1 += p * v;
    }

#pragma unroll
    for (int off = 32; off > 0; off >>= 1) {
        L  += __shfl_xor(L,  off);
        d0 += __shfl_xor(d0, off);
        d1 += __shfl_xor(d1, off);
    }

    __shared__ float sL[4], s0[4], s1[4];
    const int wave = tid >> 6, lane = tid & 63;
    if (lane == 0) { sL[wave] = L; s0[wave] = d0; s1[wave] = d1; }
    __syncthreads();
    if (tid == 0) {
        const float Lt = sL[0] + sL[1] + sL[2] + sL[3];
        const float a0 = s0[0] + s0[1] + s0[2] + s0[3];
        const float a1 = s1[0] + s1[1] + s1[2] + s1[3];
        const float inv = 1.0f / Lt;
        out[b * 2 + 0] = a0 * inv + cls_b[0];
        out[b * 2 + 1] = a1 * inv + cls_b[1];
    }
}

// ---------------------------------------------------------------------------
extern "C" void kernel_launch(void* const* d_in, const int* in_sizes, int n_in,
                              void* d_out, int out_size, void* d_ws, size_t ws_size,
                              hipStream_t stream)
{
    const int*   tokens = (const int*)  d_in[0];   // (32, 2048)
    const float* emb    = (const float*)d_in[1];   // (32000, 512)
    const float* cls_w  = (const float*)d_in[2];   // (2, 512)
    const float* cls_b  = (const float*)d_in[3];   // (2,)
    float*       out    = (float*)d_out;           // (32, 2)

    // Workspace: QT[36][512] (73.7 KB) + Sh[2][32000][36] (9.216 MB)
    float* QT = (float*)d_ws;
    float* Sh = QT + (size_t)JT * DD;

    build_qt<<<JT, 128, 0, stream>>>(tokens, emb, cls_w, QT);
    score_pass<<<dim3(125, 2), 256, 0, stream>>>(emb, QT, Sh);
    gather_pass<<<BB, 256, 0, stream>>>(tokens, Sh, cls_b, out);
}